// Round 4
// baseline (88.332 us; speedup 1.0000x reference)
//
#include <hip/hip_runtime.h>
#include <math.h>

#define BB 64          // batch
#define CC 16          // children per sample
#define DD 512         // feature dim
#define LL 8192        // CC*DD flattened length
#define EPSV 1e-8f
#define INVT 10.0f     // 1/TEMPERATURE
#define NEGINF_T (-1e31f)

// ws layout (bytes):
//  [0,      1 MB)   cib : ci as bf16, 1024 rows x 512
//  [1 MB,   2 MB)   cjb : cj as bf16
//  [2 MB,  10 MB)   D   : f32 [1024][2048]; cols [0,1024)=ci.cj^T, [1024,2048)=ci.ci^T
//  [10 MB, +4 KB)   n2i : ||ci row||^2 (fp32 exact)
//  [+4 KB, +8 KB)   n2j : ||cj row||^2
//  [+8 KB, +256 B)  pos : dot(fi,fj) per anchor (fp32 exact)
#define OFF_CIB 0
#define OFF_CJB (1u << 20)
#define OFF_D   (2u << 20)
#define OFF_N2I (10u << 20)
#define OFF_N2J ((10u << 20) + 4096u)
#define OFF_POS ((10u << 20) + 8192u)

typedef short bf16x8 __attribute__((ext_vector_type(8)));
typedef float f32x4  __attribute__((ext_vector_type(4)));

__device__ __forceinline__ float dot4(float4 a, float4 b) {
    return a.x * b.x + a.y * b.y + a.z * b.z + a.w * b.w;
}
__device__ __forceinline__ float wave_reduce(float v) {
    #pragma unroll
    for (int off = 32; off; off >>= 1) v += __shfl_down(v, off);
    return v;
}
__device__ __forceinline__ unsigned short f2bf(float f) {  // RNE bf16
    union { float f; unsigned u; } x; x.f = f;
    return (unsigned short)((x.u + 0x7fffu + ((x.u >> 16) & 1u)) >> 16);
}

// ---------------------------------------------------------------------------
// prep: blocks [0,512): wave w handles child-row r=b*4+w (0..2047): fp32 norm
//       + bf16 convert/store. blocks [512,576): fp32 positive dot for anchor.
// ---------------------------------------------------------------------------
__global__ __launch_bounds__(256) void ntx_prep(const float* __restrict__ ci,
                                                const float* __restrict__ cj,
                                                char* __restrict__ ws,
                                                float* __restrict__ out) {
    const int b = blockIdx.x, tid = threadIdx.x;
    const int wave = tid >> 6, lane = tid & 63;
    __shared__ float red[4];

    if (b < 512) {
        const int r  = b * 4 + wave;        // 0..2047
        const int rr = r & 1023;
        const bool is_i = (r < 1024);
        const float* src = is_i ? ci : cj;
        unsigned short* dst = (unsigned short*)(ws + (is_i ? OFF_CIB : OFF_CJB));
        float4 v1 = ((const float4*)(src + rr * DD))[lane];
        float4 v2 = ((const float4*)(src + rr * DD))[64 + lane];
        float acc = wave_reduce(dot4(v1, v1) + dot4(v2, v2));
        if (lane == 0) ((float*)(ws + (is_i ? OFF_N2I : OFF_N2J)))[rr] = acc;
        ushort4 h1 = { f2bf(v1.x), f2bf(v1.y), f2bf(v1.z), f2bf(v1.w) };
        ushort4 h2 = { f2bf(v2.x), f2bf(v2.y), f2bf(v2.z), f2bf(v2.w) };
        ((ushort4*)(dst + rr * DD))[lane]      = h1;
        ((ushort4*)(dst + rr * DD))[64 + lane] = h2;
    } else {
        const int i = b - 512;
        if (b == 512 && tid == 0) out[0] = 0.f;   // final accumulates atomically
        const float4* fi = (const float4*)(ci + i * LL);
        const float4* fj = (const float4*)(cj + i * LL);
        float acc = 0.f;
        #pragma unroll
        for (int it = 0; it < 8; ++it) acc += dot4(fi[tid + 256 * it], fj[tid + 256 * it]);
        acc = wave_reduce(acc);
        if (lane == 0) red[wave] = acc;
        __syncthreads();
        if (tid == 0) ((float*)(ws + OFF_POS))[i] = red[0] + red[1] + red[2] + red[3];
    }
}

// ---------------------------------------------------------------------------
// gemm: D[m][n] (1024 x 2048) = cib_row_m . (n<1024 ? cjb_row_n : cib_row_{n-1024})
// Block = 64x64 tile, 4 waves in 2x2, wave = 32x32 (2x2 MFMA tiles of 16x16x32).
// Fragment layouts (HW-verified per guide): A/B lane l holds row (l&15), k =
// (l>>4)*8..+7 (one b128); C/D: col = l&15, row = (l>>4)*4 + reg.
// ---------------------------------------------------------------------------
__global__ __launch_bounds__(256) void ntx_gemm(const char* __restrict__ ws_c,
                                                float* __restrict__ D) {
    const int bm = blockIdx.x;    // 0..15
    const int bn = blockIdx.y;    // 0..31
    const int tid = threadIdx.x;
    const int wave = tid >> 6, lane = tid & 63;
    const int wm = wave >> 1, wn = wave & 1;
    const int quad = lane >> 4, lr = lane & 15;

    const short* A = (const short*)(ws_c + OFF_CIB);
    const bool isj = (bn < 16);
    const short* B = (const short*)(ws_c + (isj ? OFF_CJB : OFF_CIB));
    const int row0 = bm * 64 + wm * 32;                    // A-row base
    const int nrow0 = (isj ? bn : bn - 16) * 64 + wn * 32; // B-row base

    f32x4 acc[2][2] = {};
    const int ka = quad * 8;

    #pragma unroll 4
    for (int kk = 0; kk < 16; ++kk) {
        const int k = kk * 32 + ka;
        bf16x8 a0 = *(const bf16x8*)(A + (row0 + lr) * DD + k);
        bf16x8 a1 = *(const bf16x8*)(A + (row0 + 16 + lr) * DD + k);
        bf16x8 b0 = *(const bf16x8*)(B + (nrow0 + lr) * DD + k);
        bf16x8 b1 = *(const bf16x8*)(B + (nrow0 + 16 + lr) * DD + k);
        acc[0][0] = __builtin_amdgcn_mfma_f32_16x16x32_bf16(a0, b0, acc[0][0], 0, 0, 0);
        acc[0][1] = __builtin_amdgcn_mfma_f32_16x16x32_bf16(a0, b1, acc[0][1], 0, 0, 0);
        acc[1][0] = __builtin_amdgcn_mfma_f32_16x16x32_bf16(a1, b0, acc[1][0], 0, 0, 0);
        acc[1][1] = __builtin_amdgcn_mfma_f32_16x16x32_bf16(a1, b1, acc[1][1], 0, 0, 0);
    }

    const int gcol0 = bn * 64 + wn * 32;
    #pragma unroll
    for (int a = 0; a < 2; ++a) {
        #pragma unroll
        for (int b = 0; b < 2; ++b) {
            const int row = row0 + a * 16 + quad * 4;
            const int col = gcol0 + b * 16 + lr;
            #pragma unroll
            for (int r = 0; r < 4; ++r)
                D[(row + r) * 2048 + col] = acc[a][b][r];
        }
    }
}

// ---------------------------------------------------------------------------
// final: block i, lane j. Gather 16+16 entries of D, normalize with fp32
// norms, masked logsumexp over 129 logits, atomicAdd loss_i/(2B).
// ---------------------------------------------------------------------------
__global__ __launch_bounds__(64) void ntx_final(const int* __restrict__ pids,
                                                const int* __restrict__ nj,
                                                const int* __restrict__ nk,
                                                const char* __restrict__ ws_c,
                                                float* __restrict__ out) {
    const int i = blockIdx.x, j = threadIdx.x;
    const float* D   = (const float*)(ws_c + OFF_D);
    const float* n2i = (const float*)(ws_c + OFF_N2I);
    const float* n2j = (const float*)(ws_c + OFF_N2J);
    const float* pos = (const float*)(ws_c + OFF_POS);

    float si = 0.f, sjf = 0.f;
    #pragma unroll
    for (int c = 0; c < CC; ++c) { si += n2i[i * CC + c]; sjf += n2j[i * CC + c]; }
    const float ni = fmaxf(sqrtf(si), EPSV);
    const float l0 = pos[i] / (ni * fmaxf(sqrtf(sjf), EPSV)) * INVT;

    int4 njv[4], nkv[4];
    #pragma unroll
    for (int t = 0; t < 4; ++t) {
        njv[t] = ((const int4*)(nj + (i * BB + j) * CC))[t];
        nkv[t] = ((const int4*)(nk + (i * BB + j) * CC))[t];
    }
    float gj = 0.f, gk = 0.f, dj = 0.f, dk = 0.f;
    #pragma unroll
    for (int t = 0; t < 4; ++t) {
        const int aj[4] = { njv[t].x, njv[t].y, njv[t].z, njv[t].w };
        const int ak[4] = { nkv[t].x, nkv[t].y, nkv[t].z, nkv[t].w };
        #pragma unroll
        for (int u = 0; u < 4; ++u) {
            const int c = t * 4 + u;
            gj += n2j[j * CC + aj[u]];
            gk += n2i[j * CC + ak[u]];
            dj += D[(i * CC + c) * 2048 + j * CC + aj[u]];
            dk += D[(i * CC + c) * 2048 + 1024 + j * CC + ak[u]];
        }
    }

    const bool valid = (j != i) && (pids[j] != pids[i]);
    float lj = NEGINF_T, lk = NEGINF_T;
    if (valid) {
        const float inv = INVT / ni;
        lj = dj / fmaxf(sqrtf(gj), EPSV) * inv;
        lk = dk / fmaxf(sqrtf(gk), EPSV) * inv;
    }

    float m = fmaxf(lj, lk);
    #pragma unroll
    for (int off = 32; off; off >>= 1) m = fmaxf(m, __shfl_xor(m, off));
    m = fmaxf(m, l0);

    float s = __expf(lj - m) + __expf(lk - m);
    s = wave_reduce(s);
    if (j == 0) {
        s += __expf(l0 - m);
        const float loss_i = -l0 + m + __logf(s);
        atomicAdd(out, loss_i * (1.0f / (2.0f * BB)));
    }
}

// ---------------------------------------------------------------------------
extern "C" void kernel_launch(void* const* d_in, const int* in_sizes, int n_in,
                              void* d_out, int out_size, void* d_ws, size_t ws_size,
                              hipStream_t stream) {
    const float* ci  = (const float*)d_in[0];
    const float* cj  = (const float*)d_in[1];
    const int*  pids = (const int*) d_in[2];
    const int*  nj   = (const int*) d_in[3];
    const int*  nk   = (const int*) d_in[4];
    char*  ws  = (char*)d_ws;
    float* out = (float*)d_out;

    ntx_prep<<<576, 256, 0, stream>>>(ci, cj, ws, out);
    ntx_gemm<<<dim3(16, 32), 256, 0, stream>>>(ws, (float*)(ws + OFF_D));
    ntx_final<<<BB, 64, 0, stream>>>(pids, nj, nk, ws, out);
}

// Round 5
// 86.465 us; speedup vs baseline: 1.0216x; 1.0216x over previous
//
#include <hip/hip_runtime.h>
#include <math.h>

#define BB 64          // batch
#define CC 16          // children per sample
#define DD 512         // feature dim
#define LL 8192        // CC*DD flattened length
#define EPSV 1e-8f
#define INVT 10.0f     // 1/TEMPERATURE
#define NEGINF_T (-1e31f)

// ws layout (bytes):
//  [0,   1 MB)  cib : ci as bf16 [1024][512]
//  [1MB, 2 MB)  cjb : cj as bf16 [1024][512]
//  2MB +0    : n2i [1024] f32   (4 KB)   ||ci row||^2 (fp32 exact)
//      +4 KB : n2j [1024] f32   (4 KB)
//      +8 KB : pos [64]   f32            dot(fi,fj) (fp32 exact)
//      +12KB : dj  [64][64] f32 (16 KB)  gathered dots vs cj
//      +28KB : dk  [64][64] f32 (16 KB)  gathered dots vs ci
//      +44KB : gj  [64][64] f32 (16 KB)  gathered sq-norm sums (cj side)
//      +60KB : gk  [64][64] f32 (16 KB)  gathered sq-norm sums (ci side)
#define OFF_CIB 0u
#define OFF_CJB (1u << 20)
#define BASE2   (2u << 20)
#define OFF_N2I (BASE2)
#define OFF_N2J (BASE2 + 4096u)
#define OFF_POS (BASE2 + 8192u)
#define OFF_DJ  (BASE2 + 12288u)
#define OFF_DK  (BASE2 + 12288u + 16384u)
#define OFF_GJ  (BASE2 + 12288u + 32768u)
#define OFF_GK  (BASE2 + 12288u + 49152u)

typedef short bf16x8 __attribute__((ext_vector_type(8)));
typedef float f32x4  __attribute__((ext_vector_type(4)));

__device__ __forceinline__ float dot4(float4 a, float4 b) {
    return a.x * b.x + a.y * b.y + a.z * b.z + a.w * b.w;
}
__device__ __forceinline__ float wave_reduce(float v) {
    #pragma unroll
    for (int off = 32; off; off >>= 1) v += __shfl_down(v, off);
    return v;
}
__device__ __forceinline__ unsigned short f2bf(float f) {  // RNE bf16
    union { float f; unsigned u; } x; x.f = f;
    return (unsigned short)((x.u + 0x7fffu + ((x.u >> 16) & 1u)) >> 16);
}

// ---------------------------------------------------------------------------
// prep: blocks [0,512): wave w handles child-row r=b*4+w: fp32 norm + bf16
//       convert/store. blocks [512,576): fp32 positive dot for anchor b-512.
// ---------------------------------------------------------------------------
__global__ __launch_bounds__(256) void ntx_prep(const float* __restrict__ ci,
                                                const float* __restrict__ cj,
                                                char* __restrict__ ws,
                                                float* __restrict__ out) {
    const int b = blockIdx.x, tid = threadIdx.x;
    const int wave = tid >> 6, lane = tid & 63;
    __shared__ float red[4];

    if (b < 512) {
        const int r  = b * 4 + wave;        // 0..2047
        const int rr = r & 1023;
        const bool is_i = (r < 1024);
        const float* src = is_i ? ci : cj;
        unsigned short* dst = (unsigned short*)(ws + (is_i ? OFF_CIB : OFF_CJB));
        float4 v1 = ((const float4*)(src + rr * DD))[lane];
        float4 v2 = ((const float4*)(src + rr * DD))[64 + lane];
        float acc = wave_reduce(dot4(v1, v1) + dot4(v2, v2));
        if (lane == 0) ((float*)(ws + (is_i ? OFF_N2I : OFF_N2J)))[rr] = acc;
        ushort4 h1 = { f2bf(v1.x), f2bf(v1.y), f2bf(v1.z), f2bf(v1.w) };
        ushort4 h2 = { f2bf(v2.x), f2bf(v2.y), f2bf(v2.z), f2bf(v2.w) };
        ((ushort4*)(dst + rr * DD))[lane]      = h1;
        ((ushort4*)(dst + rr * DD))[64 + lane] = h2;
    } else {
        const int i = b - 512;
        if (b == 512 && tid == 0) out[0] = 0.f;   // final accumulates atomically
        const float4* fi = (const float4*)(ci + i * LL);
        const float4* fj = (const float4*)(cj + i * LL);
        float acc = 0.f;
        #pragma unroll
        for (int it = 0; it < 8; ++it) acc += dot4(fi[tid + 256 * it], fj[tid + 256 * it]);
        acc = wave_reduce(acc);
        if (lane == 0) red[wave] = acc;
        __syncthreads();
        if (tid == 0) ((float*)(ws + OFF_POS))[i] = red[0] + red[1] + red[2] + red[3];
    }
}

// ---------------------------------------------------------------------------
// strip: block b -> (i = b>>2, q = b&3). side = q>>1 (0: cj/dj, 1: ci/dk),
// jh = q&1 (j in [jh*32, jh*32+32)). Computes the 16x512 strip
// S[c][x] = ci_child(i,c) . src_row(jh*512 + x) via MFMA into LDS, then
// gathers dj/gj (or dk/gk) for its 32 j's directly from LDS. No D in global.
// Fragment layouts (HW-verified): A/B lane l: row l&15, k=(l>>4)*8..+7;
// C/D: col(n)=l&15, row(m)=(l>>4)*4+reg.
// ---------------------------------------------------------------------------
__global__ __launch_bounds__(256) void ntx_strip(const int* __restrict__ nj,
                                                 const int* __restrict__ nk,
                                                 char* __restrict__ ws) {
    const int b = blockIdx.x;          // 0..255
    const int i = b >> 2, q = b & 3;
    const int side = q >> 1, jh = q & 1;
    const int tid  = threadIdx.x;
    const int wave = tid >> 6, lane = tid & 63;
    const int quad = lane >> 4, lr = lane & 15;

    __shared__ float sS[16][512];      // 32 KB strip

    const short* A  = (const short*)(ws + OFF_CIB) + i * CC * DD;
    const short* Bm = (const short*)(ws + (side ? OFF_CIB : OFF_CJB)) + jh * 512 * DD;

    f32x4 acc[8] = {};
    #pragma unroll
    for (int kk = 0; kk < 16; ++kk) {
        const int k = kk * 32 + quad * 8;
        bf16x8 av = *(const bf16x8*)(A + lr * DD + k);
        #pragma unroll
        for (int tt = 0; tt < 8; ++tt) {
            const int row = (wave * 8 + tt) * 16 + lr;   // source row in half
            bf16x8 bv = *(const bf16x8*)(Bm + row * DD + k);
            acc[tt] = __builtin_amdgcn_mfma_f32_16x16x32_bf16(av, bv, acc[tt], 0, 0, 0);
        }
    }
    #pragma unroll
    for (int tt = 0; tt < 8; ++tt) {
        const int t = wave * 8 + tt;
        #pragma unroll
        for (int r = 0; r < 4; ++r)
            sS[quad * 4 + r][t * 16 + lr] = acc[tt][r];
    }
    __syncthreads();

    // gather: 8 threads per j (32 j's), 2 children per thread
    const int jj = tid >> 3;           // 0..31 local j
    const int g  = tid & 7;
    const int j  = jh * 32 + jj;
    const int* idxp = (side ? nk : nj) + (i * BB + j) * CC;
    const float* n2 = (const float*)(ws + (side ? OFF_N2I : OFF_N2J)) + j * CC;
    const int c0 = g * 2;
    const int x0 = idxp[c0], x1 = idxp[c0 + 1];
    float d  = sS[c0][jj * 16 + x0] + sS[c0 + 1][jj * 16 + x1];
    float gn = n2[x0] + n2[x1];
    d += __shfl_down(d, 4);  gn += __shfl_down(gn, 4);
    d += __shfl_down(d, 2);  gn += __shfl_down(gn, 2);
    d += __shfl_down(d, 1);  gn += __shfl_down(gn, 1);
    if (g == 0) {
        ((float*)(ws + (side ? OFF_DK : OFF_DJ)))[i * BB + j] = d;
        ((float*)(ws + (side ? OFF_GK : OFF_GJ)))[i * BB + j] = gn;
    }
}

// ---------------------------------------------------------------------------
// final: block i, lane j. Normalize, masked logsumexp over 129 logits,
// atomicAdd loss_i/(2B) into out.
// ---------------------------------------------------------------------------
__global__ __launch_bounds__(64) void ntx_final(const int* __restrict__ pids,
                                                const char* __restrict__ ws_c,
                                                float* __restrict__ out) {
    const int i = blockIdx.x, j = threadIdx.x;
    const float* n2i = (const float*)(ws_c + OFF_N2I);
    const float* n2j = (const float*)(ws_c + OFF_N2J);
    const float* pos = (const float*)(ws_c + OFF_POS);

    float si = 0.f, sjf = 0.f;
    #pragma unroll
    for (int c = 0; c < CC; ++c) { si += n2i[i * CC + c]; sjf += n2j[i * CC + c]; }
    const float ni = fmaxf(sqrtf(si), EPSV);
    const float l0 = pos[i] / (ni * fmaxf(sqrtf(sjf), EPSV)) * INVT;

    const float dj = ((const float*)(ws_c + OFF_DJ))[i * BB + j];
    const float dk = ((const float*)(ws_c + OFF_DK))[i * BB + j];
    const float gj = ((const float*)(ws_c + OFF_GJ))[i * BB + j];
    const float gk = ((const float*)(ws_c + OFF_GK))[i * BB + j];

    const bool valid = (j != i) && (pids[j] != pids[i]);
    float lj = NEGINF_T, lk = NEGINF_T;
    if (valid) {
        const float inv = INVT / ni;
        lj = dj / fmaxf(sqrtf(gj), EPSV) * inv;
        lk = dk / fmaxf(sqrtf(gk), EPSV) * inv;
    }

    float m = fmaxf(lj, lk);
    #pragma unroll
    for (int off = 32; off; off >>= 1) m = fmaxf(m, __shfl_xor(m, off));
    m = fmaxf(m, l0);

    float s = __expf(lj - m) + __expf(lk - m);
    s = wave_reduce(s);
    if (j == 0) {
        s += __expf(l0 - m);
        const float loss_i = -l0 + m + __logf(s);
        atomicAdd(out, loss_i * (1.0f / (2.0f * BB)));
    }
}

// ---------------------------------------------------------------------------
extern "C" void kernel_launch(void* const* d_in, const int* in_sizes, int n_in,
                              void* d_out, int out_size, void* d_ws, size_t ws_size,
                              hipStream_t stream) {
    const float* ci  = (const float*)d_in[0];
    const float* cj  = (const float*)d_in[1];
    const int*  pids = (const int*) d_in[2];
    const int*  nj   = (const int*) d_in[3];
    const int*  nk   = (const int*) d_in[4];
    char*  ws  = (char*)d_ws;
    float* out = (float*)d_out;

    ntx_prep<<<576, 256, 0, stream>>>(ci, cj, ws, out);
    ntx_strip<<<256, 256, 0, stream>>>(nj, nk, ws);
    ntx_final<<<BB, 64, 0, stream>>>(pids, ws, out);
}